// Round 3
// baseline (262.885 us; speedup 1.0000x reference)
//
#include <hip/hip_runtime.h>
#include <math.h>

#define NN 50000
#define NE 800000
#define KD 256
#define OD 64
#define NCH ((NN + 255) / 256)

using bf16x8 = __attribute__((ext_vector_type(8))) short;
using f32x4  = __attribute__((ext_vector_type(4))) float;

__device__ __forceinline__ unsigned short f2b(float x) {
    union { float f; unsigned u; } c; c.f = x;
    unsigned r = (c.u + 0x7FFF + ((c.u >> 16) & 1)) >> 16;
    return (unsigned short)r;
}
__device__ __forceinline__ float b2f(unsigned short b) {
    union { unsigned u; float f; } c; c.u = ((unsigned)b) << 16;
    return c.f;
}

// ---------------- CSR build ----------------

__global__ void k_count(const int* __restrict__ dst, int* __restrict__ deg) {
    int e = blockIdx.x * 256 + threadIdx.x;
    if (e < NE) atomicAdd(&deg[dst[e]], 1);
}

__global__ void k_chunk_sum(const int* __restrict__ deg, int* __restrict__ chunkSum) {
    __shared__ int s[256];
    int g = blockIdx.x * 256 + threadIdx.x;
    s[threadIdx.x] = (g < NN) ? deg[g] : 0;
    __syncthreads();
    for (int o = 128; o > 0; o >>= 1) {
        if (threadIdx.x < o) s[threadIdx.x] += s[threadIdx.x + o];
        __syncthreads();
    }
    if (threadIdx.x == 0) chunkSum[blockIdx.x] = s[0];
}

__global__ void k_scan_chunks(const int* __restrict__ chunkSum, int* __restrict__ chunkOff) {
    if (threadIdx.x == 0 && blockIdx.x == 0) {
        int acc = 0;
        for (int i = 0; i < NCH; ++i) { chunkOff[i] = acc; acc += chunkSum[i]; }
    }
}

__global__ void k_scan_write(const int* __restrict__ deg, const int* __restrict__ chunkOff,
                             int* __restrict__ offsets, int* __restrict__ cursor) {
    __shared__ int s[256];
    int b = blockIdx.x, t = threadIdx.x;
    int g = b * 256 + t;
    int v = (g < NN) ? deg[g] : 0;
    s[t] = v;
    __syncthreads();
    for (int o = 1; o < 256; o <<= 1) {
        int x = (t >= o) ? s[t - o] : 0;
        __syncthreads();
        s[t] += x;
        __syncthreads();
    }
    int excl = s[t] - v + chunkOff[b];
    if (g <= NN) {
        offsets[g] = excl;
        if (g < NN) cursor[g] = excl;
    }
}

__global__ void k_scatter(const int* __restrict__ src, const int* __restrict__ dst,
                          const float* __restrict__ w, int* __restrict__ cursor,
                          int* __restrict__ psrc, float* __restrict__ pw) {
    int e = blockIdx.x * 256 + threadIdx.x;
    if (e < NE) {
        int d = dst[e];
        int p = atomicAdd(&cursor[d], 1);
        psrc[p] = src[e];
        pw[p]  = w[e];
    }
}

// ---------------- weight transpose + bf16 convert (one-time, tiny) ----------------

__global__ void k_convW(const float* __restrict__ hw, const float* __restrict__ mw_,
                        const float* __restrict__ lw,
                        unsigned short* __restrict__ Wht, unsigned short* __restrict__ Wmlt) {
    int idx = blockIdx.x * 256 + threadIdx.x;
    if (idx < 256 * 256) {
        int n = idx >> 8, k = idx & 255;
        Wht[(size_t)n * 256 + k] = f2b(hw[(size_t)k * 256 + n]);
    }
    if (idx < 128 * 256) {
        int n = idx >> 8, k = idx & 255;
        float v = (n < 64) ? mw_[(size_t)k * 64 + n] : lw[(size_t)k * 64 + (n - 64)];
        Wmlt[(size_t)n * 256 + k] = f2b(v);
    }
}

// ---------------- MFMA GEMM: 128x128 block tile, 4 waves, wave-tile 64x64 ----------------
// AM: 0 = A f32 (convert on the fly); 1 = A bf16; 2 = A bf16 + hbias + relu
// EM: 0 = store bf16 (ldOut); 1 = store f32 + bias into d_out regions

template <int AM, int EM>
__global__ __launch_bounds__(256) void k_gemm(const void* __restrict__ Ap,
                                              const unsigned short* __restrict__ Bt,
                                              const float* __restrict__ hbias,
                                              const float* __restrict__ mbias,
                                              const float* __restrict__ lbias,
                                              void* __restrict__ Outp,
                                              int ldOut) {
    __shared__ unsigned short As[128 * 64];
    __shared__ unsigned short Bs[128 * 64];
    const int tid = threadIdx.x;
    const int row0 = blockIdx.x * 128;
    const int n0 = blockIdx.y * 128;
    const int lane = tid & 63;
    const int w = tid >> 6, wm = w >> 1, wn = w & 1;
    const int lr = lane & 15, lg = lane >> 4;
    const int r = tid >> 1;       // staging row 0..127
    const int h = tid & 1;        // k-half (32 bf16)

    f32x4 acc[4][4] = {};

    for (int k0 = 0; k0 < KD; k0 += 64) {
        // ---- stage A (128 rows x 64 k bf16, XOR-swizzled 16B slots) ----
        {
            int gr = row0 + r;
            unsigned short tmp[32];
            if (AM == 0) {
                const float* A = (const float*)Ap;
                if (gr < NN) {
                    #pragma unroll
                    for (int i = 0; i < 8; ++i) {
                        float4 v = *reinterpret_cast<const float4*>(
                            &A[(size_t)gr * KD + k0 + h * 32 + i * 4]);
                        tmp[i * 4 + 0] = f2b(v.x); tmp[i * 4 + 1] = f2b(v.y);
                        tmp[i * 4 + 2] = f2b(v.z); tmp[i * 4 + 3] = f2b(v.w);
                    }
                } else {
                    #pragma unroll
                    for (int i = 0; i < 32; ++i) tmp[i] = 0;
                }
            } else {
                const unsigned short* A = (const unsigned short*)Ap;
                if (gr < NN) {
                    #pragma unroll
                    for (int i = 0; i < 4; ++i)
                        *reinterpret_cast<uint4*>(&tmp[i * 8]) =
                            *reinterpret_cast<const uint4*>(&A[(size_t)gr * KD + k0 + h * 32 + i * 8]);
                    if (AM == 2) {
                        #pragma unroll
                        for (int i = 0; i < 8; ++i) {
                            float4 hb4 = *reinterpret_cast<const float4*>(&hbias[k0 + h * 32 + i * 4]);
                            tmp[i * 4 + 0] = f2b(fmaxf(b2f(tmp[i * 4 + 0]) + hb4.x, 0.f));
                            tmp[i * 4 + 1] = f2b(fmaxf(b2f(tmp[i * 4 + 1]) + hb4.y, 0.f));
                            tmp[i * 4 + 2] = f2b(fmaxf(b2f(tmp[i * 4 + 2]) + hb4.z, 0.f));
                            tmp[i * 4 + 3] = f2b(fmaxf(b2f(tmp[i * 4 + 3]) + hb4.w, 0.f));
                        }
                    }
                } else {
                    #pragma unroll
                    for (int i = 0; i < 32; ++i) tmp[i] = 0;
                }
            }
            #pragma unroll
            for (int i = 0; i < 4; ++i) {
                int slot = (h * 4 + i) ^ (r & 7);
                *reinterpret_cast<uint4*>(&As[r * 64 + slot * 8]) =
                    *reinterpret_cast<const uint4*>(&tmp[i * 8]);
            }
        }
        // ---- stage B (Bt [N][K] bf16 row-major) ----
        {
            const unsigned short* B = Bt + (size_t)(n0 + r) * KD + k0 + h * 32;
            #pragma unroll
            for (int i = 0; i < 4; ++i) {
                uint4 u = *reinterpret_cast<const uint4*>(B + i * 8);
                int slot = (h * 4 + i) ^ (r & 7);
                *reinterpret_cast<uint4*>(&Bs[r * 64 + slot * 8]) = u;
            }
        }
        __syncthreads();
        // ---- MFMA: wave 64x64, fragments 4x4, 2 K-slices of 32 ----
        const int sa = lr & 7;
        #pragma unroll
        for (int ks = 0; ks < 2; ++ks) {
            int slot = ks * 4 + lg;
            bf16x8 a[4], b[4];
            #pragma unroll
            for (int fm = 0; fm < 4; ++fm) {
                int ra = wm * 64 + fm * 16 + lr;
                a[fm] = *reinterpret_cast<const bf16x8*>(&As[ra * 64 + (slot ^ sa) * 8]);
            }
            #pragma unroll
            for (int fn = 0; fn < 4; ++fn) {
                int rb = wn * 64 + fn * 16 + lr;
                b[fn] = *reinterpret_cast<const bf16x8*>(&Bs[rb * 64 + (slot ^ sa) * 8]);
            }
            #pragma unroll
            for (int fm = 0; fm < 4; ++fm)
                #pragma unroll
                for (int fn = 0; fn < 4; ++fn)
                    acc[fm][fn] = __builtin_amdgcn_mfma_f32_16x16x32_bf16(a[fm], b[fn], acc[fm][fn], 0, 0, 0);
        }
        __syncthreads();
    }
    // ---- epilogue: C/D col=lane&15, row=(lane>>4)*4+reg ----
    #pragma unroll
    for (int fm = 0; fm < 4; ++fm) {
        #pragma unroll
        for (int j = 0; j < 4; ++j) {
            int grow = row0 + wm * 64 + fm * 16 + lg * 4 + j;
            if (grow >= NN) continue;
            #pragma unroll
            for (int fn = 0; fn < 4; ++fn) {
                int gcol = n0 + wn * 64 + fn * 16 + lr;
                float v = acc[fm][fn][j];
                if (EM == 0) {
                    ((unsigned short*)Outp)[(size_t)grow * ldOut + gcol] = f2b(v);
                } else {
                    float* out = (float*)Outp;
                    int region = gcol >> 6;
                    int oc = gcol & 63;
                    float b = region ? lbias[oc] : mbias[oc];
                    out[(size_t)region * NN * OD + (size_t)grow * OD + oc] = v + b;
                }
            }
        }
    }
}

// ---------------- SpMM1 + bias + relu (bf16 gather), 4 dsts / 256-thread block ----------------

__global__ __launch_bounds__(256) void k_spmm1(const int* __restrict__ off, const int* __restrict__ psrc,
                                               const float* __restrict__ pw,
                                               const unsigned short* __restrict__ sup,
                                               const float* __restrict__ bias,
                                               unsigned short* __restrict__ hg) {
    int lane = threadIdx.x & 63;
    int d = blockIdx.x * 4 + (threadIdx.x >> 6);
    int e0 = off[d], e1 = off[d + 1];
    float a0 = 0.f, a1 = 0.f, a2 = 0.f, a3 = 0.f;
    const ushort4* S = reinterpret_cast<const ushort4*>(sup);   // 64 ushort4 per row
    int e = e0;
    for (; e + 4 <= e1; e += 4) {
        int s0 = psrc[e], s1 = psrc[e + 1], s2 = psrc[e + 2], s3 = psrc[e + 3];
        float w0 = pw[e], w1 = pw[e + 1], w2 = pw[e + 2], w3 = pw[e + 3];
        ushort4 v0 = S[(size_t)s0 * 64 + lane];
        ushort4 v1 = S[(size_t)s1 * 64 + lane];
        ushort4 v2 = S[(size_t)s2 * 64 + lane];
        ushort4 v3 = S[(size_t)s3 * 64 + lane];
        a0 += w0 * b2f(v0.x) + w1 * b2f(v1.x) + w2 * b2f(v2.x) + w3 * b2f(v3.x);
        a1 += w0 * b2f(v0.y) + w1 * b2f(v1.y) + w2 * b2f(v2.y) + w3 * b2f(v3.y);
        a2 += w0 * b2f(v0.z) + w1 * b2f(v1.z) + w2 * b2f(v2.z) + w3 * b2f(v3.z);
        a3 += w0 * b2f(v0.w) + w1 * b2f(v1.w) + w2 * b2f(v2.w) + w3 * b2f(v3.w);
    }
    for (; e < e1; ++e) {
        int s = psrc[e];
        float w = pw[e];
        ushort4 v = S[(size_t)s * 64 + lane];
        a0 += w * b2f(v.x); a1 += w * b2f(v.y); a2 += w * b2f(v.z); a3 += w * b2f(v.w);
    }
    float4 b = *reinterpret_cast<const float4*>(&bias[lane * 4]);
    ushort4 o;
    o.x = f2b(fmaxf(a0 + b.x, 0.f));
    o.y = f2b(fmaxf(a1 + b.y, 0.f));
    o.z = f2b(fmaxf(a2 + b.z, 0.f));
    o.w = f2b(fmaxf(a3 + b.w, 0.f));
    reinterpret_cast<ushort4*>(hg)[(size_t)d * 64 + lane] = o;
}

// ---------------- SpMM2 (bf16 gather, 128 dims) + mixture combine, 4 dsts / block ----------------

__global__ __launch_bounds__(256) void k_spmm2(const int* __restrict__ off, const int* __restrict__ psrc,
                                               const float* __restrict__ pw,
                                               const unsigned short* __restrict__ gp,
                                               const float* __restrict__ mixw,
                                               float* __restrict__ out) {
    int lane = threadIdx.x & 63;
    int d = blockIdx.x * 4 + (threadIdx.x >> 6);
    int e0 = off[d], e1 = off[d + 1];
    float a0 = 0.f, a1 = 0.f;
    const ushort2* G = reinterpret_cast<const ushort2*>(gp);    // 64 ushort2 per row
    int e = e0;
    for (; e + 4 <= e1; e += 4) {
        int s0 = psrc[e], s1 = psrc[e + 1], s2 = psrc[e + 2], s3 = psrc[e + 3];
        float w0 = pw[e], w1 = pw[e + 1], w2 = pw[e + 2], w3 = pw[e + 3];
        ushort2 v0 = G[(size_t)s0 * 64 + lane];
        ushort2 v1 = G[(size_t)s1 * 64 + lane];
        ushort2 v2 = G[(size_t)s2 * 64 + lane];
        ushort2 v3 = G[(size_t)s3 * 64 + lane];
        a0 += w0 * b2f(v0.x) + w1 * b2f(v1.x) + w2 * b2f(v2.x) + w3 * b2f(v3.x);
        a1 += w0 * b2f(v0.y) + w1 * b2f(v1.y) + w2 * b2f(v2.y) + w3 * b2f(v3.y);
    }
    for (; e < e1; ++e) {
        int s = psrc[e];
        float w = pw[e];
        ushort2 v = G[(size_t)s * 64 + lane];
        a0 += w * b2f(v.x); a1 += w * b2f(v.y);
    }
    float mw = mixw[0];
    float mr = 1.f / (1.f + expf(-mw));
    int c = lane * 2;
    if (c < 64) {
        float* om = out + (size_t)d * OD + c;
        om[0] = a0 * mw + om[0] * (1.f - mw);
        om[1] = a1 * mw + om[1] * (1.f - mw);
    } else {
        float* ol = out + (size_t)NN * OD + (size_t)d * OD + (c - 64);
        ol[0] = a0 * mr + ol[0] * (1.f - mr);
        ol[1] = a1 * mr + ol[1] * (1.f - mr);
    }
}

// ---------------- host ----------------

extern "C" void kernel_launch(void* const* d_in, const int* in_sizes, int n_in,
                              void* d_out, int out_size, void* d_ws, size_t ws_size,
                              hipStream_t stream) {
    const float* input = (const float*)d_in[0];
    const int*   ei    = (const int*)d_in[1];
    const float* ew    = (const float*)d_in[2];
    const float* mixw  = (const float*)d_in[3];
    const float* hw    = (const float*)d_in[4];
    const float* hb    = (const float*)d_in[5];
    const float* mw_   = (const float*)d_in[6];
    const float* mb    = (const float*)d_in[7];
    const float* lw    = (const float*)d_in[8];
    const float* lb    = (const float*)d_in[9];
    float* out = (float*)d_out;

    const int* src = ei;
    const int* dst = ei + NE;

    char* ws = (char*)d_ws;
    size_t off = 0;
    auto alloc = [&](size_t bytes) -> void* {
        void* p = ws + off;
        off += (bytes + 255) & ~(size_t)255;
        return p;
    };
    int*   deg      = (int*)alloc((size_t)NN * 4);
    int*   offsets  = (int*)alloc((size_t)(NN + 1) * 4);
    int*   cursor   = (int*)alloc((size_t)NN * 4);
    int*   chunkSum = (int*)alloc((size_t)NCH * 4);
    int*   chunkOff = (int*)alloc((size_t)NCH * 4);
    int*   psrc     = (int*)alloc((size_t)NE * 4);
    float* pw       = (float*)alloc((size_t)NE * 4);
    unsigned short* Wht  = (unsigned short*)alloc((size_t)256 * 256 * 2);
    unsigned short* Wmlt = (unsigned short*)alloc((size_t)128 * 256 * 2);
    unsigned short* support  = (unsigned short*)alloc((size_t)NN * KD * 2);
    unsigned short* hidden_g = (unsigned short*)alloc((size_t)NN * KD * 2);
    unsigned short* gcn_pre  = (unsigned short*)alloc((size_t)NN * 128 * 2);

    hipMemsetAsync(deg, 0, (size_t)NN * 4, stream);

    int eblk = (NE + 255) / 256;
    k_count<<<eblk, 256, 0, stream>>>(dst, deg);
    k_chunk_sum<<<NCH, 256, 0, stream>>>(deg, chunkSum);
    k_scan_chunks<<<1, 64, 0, stream>>>(chunkSum, chunkOff);
    k_scan_write<<<NCH, 256, 0, stream>>>(deg, chunkOff, offsets, cursor);
    k_scatter<<<eblk, 256, 0, stream>>>(src, dst, ew, cursor, psrc, pw);

    k_convW<<<256, 256, 0, stream>>>(hw, mw_, lw, Wht, Wmlt);

    int mblk = (NN + 127) / 128;   // 391
    // GEMM1: support(bf16) = bf16(input) @ hw   (N=256 -> y=2)
    k_gemm<0, 0><<<dim3(mblk, 2), 256, 0, stream>>>(input, Wht, hb, mb, lb, support, 256);
    // SpMM1 + bias + relu -> hidden_g (bf16)
    k_spmm1<<<NN / 4, 256, 0, stream>>>(offsets, psrc, pw, support, hb, hidden_g);
    // GEMM2 (GCN): gcn_pre(bf16) = hidden_g @ [mw|lw]   (N=128 -> y=1)
    k_gemm<1, 0><<<dim3(mblk, 1), 256, 0, stream>>>(hidden_g, Wmlt, hb, mb, lb, gcn_pre, 128);
    // GEMM2 (MLP): d_out = relu(support+hb) @ [mw|lw] + [mb|lb]
    k_gemm<2, 1><<<dim3(mblk, 1), 256, 0, stream>>>(support, Wmlt, hb, mb, lb, out, 128);
    // SpMM2 + mixture combine (in place on d_out)
    k_spmm2<<<NN / 4, 256, 0, stream>>>(offsets, psrc, pw, gcn_pre, mixw, out);
}

// Round 4
// 259.949 us; speedup vs baseline: 1.0113x; 1.0113x over previous
//
#include <hip/hip_runtime.h>
#include <math.h>

#define NN 50000
#define NE 800000
#define KD 256
#define OD 64
#define NCH ((NN + 255) / 256)   // 196 <= 256

using bf16x8 = __attribute__((ext_vector_type(8))) short;
using f32x4  = __attribute__((ext_vector_type(4))) float;

__device__ __forceinline__ unsigned short f2b(float x) {
    union { float f; unsigned u; } c; c.f = x;
    unsigned r = (c.u + 0x7FFF + ((c.u >> 16) & 1)) >> 16;
    return (unsigned short)r;
}
__device__ __forceinline__ float b2f(unsigned short b) {
    union { unsigned u; float f; } c; c.u = ((unsigned)b) << 16;
    return c.f;
}

// ---------------- CSR build ----------------

__global__ void k_count(const int* __restrict__ dst, int* __restrict__ deg) {
    int e = blockIdx.x * 256 + threadIdx.x;
    if (e < NE) atomicAdd(&deg[dst[e]], 1);
}

__global__ void k_chunk_sum(const int* __restrict__ deg, int* __restrict__ chunkSum) {
    __shared__ int s[256];
    int g = blockIdx.x * 256 + threadIdx.x;
    s[threadIdx.x] = (g < NN) ? deg[g] : 0;
    __syncthreads();
    for (int o = 128; o > 0; o >>= 1) {
        if (threadIdx.x < o) s[threadIdx.x] += s[threadIdx.x + o];
        __syncthreads();
    }
    if (threadIdx.x == 0) chunkSum[blockIdx.x] = s[0];
}

// parallel single-block exclusive scan over NCH chunk sums (was serial 1-thread!)
__global__ void k_scan_chunks(const int* __restrict__ chunkSum, int* __restrict__ chunkOff) {
    __shared__ int s[256];
    int t = threadIdx.x;
    int v = (t < NCH) ? chunkSum[t] : 0;
    s[t] = v;
    __syncthreads();
    for (int o = 1; o < 256; o <<= 1) {
        int x = (t >= o) ? s[t - o] : 0;
        __syncthreads();
        s[t] += x;
        __syncthreads();
    }
    if (t < NCH) chunkOff[t] = s[t] - v;
}

__global__ void k_scan_write(const int* __restrict__ deg, const int* __restrict__ chunkOff,
                             int* __restrict__ offsets, int* __restrict__ cursor) {
    __shared__ int s[256];
    int b = blockIdx.x, t = threadIdx.x;
    int g = b * 256 + t;
    int v = (g < NN) ? deg[g] : 0;
    s[t] = v;
    __syncthreads();
    for (int o = 1; o < 256; o <<= 1) {
        int x = (t >= o) ? s[t - o] : 0;
        __syncthreads();
        s[t] += x;
        __syncthreads();
    }
    int excl = s[t] - v + chunkOff[b];
    if (g <= NN) {
        offsets[g] = excl;
        if (g < NN) cursor[g] = excl;
    }
}

// pack (src, weight-bits) into int2 for single dwordx2 edge loads
__global__ void k_scatter(const int* __restrict__ src, const int* __restrict__ dst,
                          const float* __restrict__ w, int* __restrict__ cursor,
                          int2* __restrict__ pedge) {
    int e = blockIdx.x * 256 + threadIdx.x;
    if (e < NE) {
        int d = dst[e];
        int p = atomicAdd(&cursor[d], 1);
        pedge[p] = make_int2(src[e], __float_as_int(w[e]));
    }
}

// ---------------- weight transpose + bf16 convert (one-time, tiny) ----------------

__global__ void k_convW(const float* __restrict__ hw, const float* __restrict__ mw_,
                        const float* __restrict__ lw,
                        unsigned short* __restrict__ Wht, unsigned short* __restrict__ Wmlt) {
    int idx = blockIdx.x * 256 + threadIdx.x;
    if (idx < 256 * 256) {
        int n = idx >> 8, k = idx & 255;
        Wht[(size_t)n * 256 + k] = f2b(hw[(size_t)k * 256 + n]);
    }
    if (idx < 128 * 256) {
        int n = idx >> 8, k = idx & 255;
        float v = (n < 64) ? mw_[(size_t)k * 64 + n] : lw[(size_t)k * 64 + (n - 64)];
        Wmlt[(size_t)n * 256 + k] = f2b(v);
    }
}

// ---------------- MFMA GEMM: 128x128 block tile, 4 waves, wave-tile 64x64 ----------------
// AM: 0 = A f32 (convert on the fly); 1 = A bf16; 2 = A bf16 + hbias + relu
// EM: 0 = store bf16 (ldOut); 1 = store f32 + bias into d_out regions

template <int AM, int EM>
__global__ __launch_bounds__(256) void k_gemm(const void* __restrict__ Ap,
                                              const unsigned short* __restrict__ Bt,
                                              const float* __restrict__ hbias,
                                              const float* __restrict__ mbias,
                                              const float* __restrict__ lbias,
                                              void* __restrict__ Outp,
                                              int ldOut) {
    __shared__ unsigned short As[128 * 64];
    __shared__ unsigned short Bs[128 * 64];
    const int tid = threadIdx.x;
    const int row0 = blockIdx.x * 128;
    const int n0 = blockIdx.y * 128;
    const int lane = tid & 63;
    const int w = tid >> 6, wm = w >> 1, wn = w & 1;
    const int lr = lane & 15, lg = lane >> 4;
    const int r = tid >> 1;       // staging row 0..127
    const int h = tid & 1;        // k-half (32 bf16)

    f32x4 acc[4][4] = {};

    for (int k0 = 0; k0 < KD; k0 += 64) {
        {
            int gr = row0 + r;
            unsigned short tmp[32];
            if (AM == 0) {
                const float* A = (const float*)Ap;
                if (gr < NN) {
                    #pragma unroll
                    for (int i = 0; i < 8; ++i) {
                        float4 v = *reinterpret_cast<const float4*>(
                            &A[(size_t)gr * KD + k0 + h * 32 + i * 4]);
                        tmp[i * 4 + 0] = f2b(v.x); tmp[i * 4 + 1] = f2b(v.y);
                        tmp[i * 4 + 2] = f2b(v.z); tmp[i * 4 + 3] = f2b(v.w);
                    }
                } else {
                    #pragma unroll
                    for (int i = 0; i < 32; ++i) tmp[i] = 0;
                }
            } else {
                const unsigned short* A = (const unsigned short*)Ap;
                if (gr < NN) {
                    #pragma unroll
                    for (int i = 0; i < 4; ++i)
                        *reinterpret_cast<uint4*>(&tmp[i * 8]) =
                            *reinterpret_cast<const uint4*>(&A[(size_t)gr * KD + k0 + h * 32 + i * 8]);
                    if (AM == 2) {
                        #pragma unroll
                        for (int i = 0; i < 8; ++i) {
                            float4 hb4 = *reinterpret_cast<const float4*>(&hbias[k0 + h * 32 + i * 4]);
                            tmp[i * 4 + 0] = f2b(fmaxf(b2f(tmp[i * 4 + 0]) + hb4.x, 0.f));
                            tmp[i * 4 + 1] = f2b(fmaxf(b2f(tmp[i * 4 + 1]) + hb4.y, 0.f));
                            tmp[i * 4 + 2] = f2b(fmaxf(b2f(tmp[i * 4 + 2]) + hb4.z, 0.f));
                            tmp[i * 4 + 3] = f2b(fmaxf(b2f(tmp[i * 4 + 3]) + hb4.w, 0.f));
                        }
                    }
                } else {
                    #pragma unroll
                    for (int i = 0; i < 32; ++i) tmp[i] = 0;
                }
            }
            #pragma unroll
            for (int i = 0; i < 4; ++i) {
                int slot = (h * 4 + i) ^ (r & 7);
                *reinterpret_cast<uint4*>(&As[r * 64 + slot * 8]) =
                    *reinterpret_cast<const uint4*>(&tmp[i * 8]);
            }
        }
        {
            const unsigned short* B = Bt + (size_t)(n0 + r) * KD + k0 + h * 32;
            #pragma unroll
            for (int i = 0; i < 4; ++i) {
                uint4 u = *reinterpret_cast<const uint4*>(B + i * 8);
                int slot = (h * 4 + i) ^ (r & 7);
                *reinterpret_cast<uint4*>(&Bs[r * 64 + slot * 8]) = u;
            }
        }
        __syncthreads();
        const int sa = lr & 7;
        #pragma unroll
        for (int ks = 0; ks < 2; ++ks) {
            int slot = ks * 4 + lg;
            bf16x8 a[4], b[4];
            #pragma unroll
            for (int fm = 0; fm < 4; ++fm) {
                int ra = wm * 64 + fm * 16 + lr;
                a[fm] = *reinterpret_cast<const bf16x8*>(&As[ra * 64 + (slot ^ sa) * 8]);
            }
            #pragma unroll
            for (int fn = 0; fn < 4; ++fn) {
                int rb = wn * 64 + fn * 16 + lr;
                b[fn] = *reinterpret_cast<const bf16x8*>(&Bs[rb * 64 + (slot ^ sa) * 8]);
            }
            #pragma unroll
            for (int fm = 0; fm < 4; ++fm)
                #pragma unroll
                for (int fn = 0; fn < 4; ++fn)
                    acc[fm][fn] = __builtin_amdgcn_mfma_f32_16x16x32_bf16(a[fm], b[fn], acc[fm][fn], 0, 0, 0);
        }
        __syncthreads();
    }
    #pragma unroll
    for (int fm = 0; fm < 4; ++fm) {
        #pragma unroll
        for (int j = 0; j < 4; ++j) {
            int grow = row0 + wm * 64 + fm * 16 + lg * 4 + j;
            if (grow >= NN) continue;
            #pragma unroll
            for (int fn = 0; fn < 4; ++fn) {
                int gcol = n0 + wn * 64 + fn * 16 + lr;
                float v = acc[fm][fn][j];
                if (EM == 0) {
                    ((unsigned short*)Outp)[(size_t)grow * ldOut + gcol] = f2b(v);
                } else {
                    float* out = (float*)Outp;
                    int region = gcol >> 6;
                    int oc = gcol & 63;
                    float b = region ? lbias[oc] : mbias[oc];
                    out[(size_t)region * NN * OD + (size_t)grow * OD + oc] = v + b;
                }
            }
        }
    }
}

// ---------------- SpMM1 + bias + relu (bf16 gather), 4 dsts/block, unroll 8 ----------------

__global__ __launch_bounds__(256) void k_spmm1(const int* __restrict__ off,
                                               const int2* __restrict__ pedge,
                                               const unsigned short* __restrict__ sup,
                                               const float* __restrict__ bias,
                                               unsigned short* __restrict__ hg) {
    int lane = threadIdx.x & 63;
    int d = blockIdx.x * 4 + (threadIdx.x >> 6);
    int e0 = off[d], e1 = off[d + 1];
    float a0 = 0.f, a1 = 0.f, a2 = 0.f, a3 = 0.f;
    const ushort4* S = reinterpret_cast<const ushort4*>(sup);
    int e = e0;
    for (; e + 8 <= e1; e += 8) {
        int2 E[8];
        ushort4 V[8];
        #pragma unroll
        for (int i = 0; i < 8; ++i) E[i] = pedge[e + i];
        #pragma unroll
        for (int i = 0; i < 8; ++i) V[i] = S[(size_t)E[i].x * 64 + lane];
        #pragma unroll
        for (int i = 0; i < 8; ++i) {
            float w = __int_as_float(E[i].y);
            a0 = fmaf(w, b2f(V[i].x), a0);
            a1 = fmaf(w, b2f(V[i].y), a1);
            a2 = fmaf(w, b2f(V[i].z), a2);
            a3 = fmaf(w, b2f(V[i].w), a3);
        }
    }
    for (; e < e1; ++e) {
        int2 E = pedge[e];
        float w = __int_as_float(E.y);
        ushort4 v = S[(size_t)E.x * 64 + lane];
        a0 = fmaf(w, b2f(v.x), a0);
        a1 = fmaf(w, b2f(v.y), a1);
        a2 = fmaf(w, b2f(v.z), a2);
        a3 = fmaf(w, b2f(v.w), a3);
    }
    float4 b = *reinterpret_cast<const float4*>(&bias[lane * 4]);
    ushort4 o;
    o.x = f2b(fmaxf(a0 + b.x, 0.f));
    o.y = f2b(fmaxf(a1 + b.y, 0.f));
    o.z = f2b(fmaxf(a2 + b.z, 0.f));
    o.w = f2b(fmaxf(a3 + b.w, 0.f));
    reinterpret_cast<ushort4*>(hg)[(size_t)d * 64 + lane] = o;
}

// ---------------- SpMM2 (bf16 gather, 128 dims) + mixture, 4 dsts/block, unroll 8 ----------------

__global__ __launch_bounds__(256) void k_spmm2(const int* __restrict__ off,
                                               const int2* __restrict__ pedge,
                                               const unsigned short* __restrict__ gp,
                                               const float* __restrict__ mixw,
                                               float* __restrict__ out) {
    int lane = threadIdx.x & 63;
    int d = blockIdx.x * 4 + (threadIdx.x >> 6);
    int e0 = off[d], e1 = off[d + 1];
    float a0 = 0.f, a1 = 0.f;
    const ushort2* G = reinterpret_cast<const ushort2*>(gp);
    int e = e0;
    for (; e + 8 <= e1; e += 8) {
        int2 E[8];
        ushort2 V[8];
        #pragma unroll
        for (int i = 0; i < 8; ++i) E[i] = pedge[e + i];
        #pragma unroll
        for (int i = 0; i < 8; ++i) V[i] = G[(size_t)E[i].x * 64 + lane];
        #pragma unroll
        for (int i = 0; i < 8; ++i) {
            float w = __int_as_float(E[i].y);
            a0 = fmaf(w, b2f(V[i].x), a0);
            a1 = fmaf(w, b2f(V[i].y), a1);
        }
    }
    for (; e < e1; ++e) {
        int2 E = pedge[e];
        float w = __int_as_float(E.y);
        ushort2 v = G[(size_t)E.x * 64 + lane];
        a0 = fmaf(w, b2f(v.x), a0);
        a1 = fmaf(w, b2f(v.y), a1);
    }
    float mw = mixw[0];
    float mr = 1.f / (1.f + expf(-mw));
    int c = lane * 2;
    if (c < 64) {
        float2* om = reinterpret_cast<float2*>(out + (size_t)d * OD + c);
        float2 m = *om;
        *om = make_float2(a0 * mw + m.x * (1.f - mw), a1 * mw + m.y * (1.f - mw));
    } else {
        float2* ol = reinterpret_cast<float2*>(out + (size_t)NN * OD + (size_t)d * OD + (c - 64));
        float2 m = *ol;
        *ol = make_float2(a0 * mr + m.x * (1.f - mr), a1 * mr + m.y * (1.f - mr));
    }
}

// ---------------- host ----------------

extern "C" void kernel_launch(void* const* d_in, const int* in_sizes, int n_in,
                              void* d_out, int out_size, void* d_ws, size_t ws_size,
                              hipStream_t stream) {
    const float* input = (const float*)d_in[0];
    const int*   ei    = (const int*)d_in[1];
    const float* ew    = (const float*)d_in[2];
    const float* mixw  = (const float*)d_in[3];
    const float* hw    = (const float*)d_in[4];
    const float* hb    = (const float*)d_in[5];
    const float* mw_   = (const float*)d_in[6];
    const float* mb    = (const float*)d_in[7];
    const float* lw    = (const float*)d_in[8];
    const float* lb    = (const float*)d_in[9];
    float* out = (float*)d_out;

    const int* src = ei;
    const int* dst = ei + NE;

    char* ws = (char*)d_ws;
    size_t off = 0;
    auto alloc = [&](size_t bytes) -> void* {
        void* p = ws + off;
        off += (bytes + 255) & ~(size_t)255;
        return p;
    };
    int*   deg      = (int*)alloc((size_t)NN * 4);
    int*   offsets  = (int*)alloc((size_t)(NN + 1) * 4);
    int*   cursor   = (int*)alloc((size_t)NN * 4);
    int*   chunkSum = (int*)alloc((size_t)NCH * 4);
    int*   chunkOff = (int*)alloc((size_t)NCH * 4);
    int2*  pedge    = (int2*)alloc((size_t)NE * 8);
    unsigned short* Wht  = (unsigned short*)alloc((size_t)256 * 256 * 2);
    unsigned short* Wmlt = (unsigned short*)alloc((size_t)128 * 256 * 2);
    unsigned short* support  = (unsigned short*)alloc((size_t)NN * KD * 2);
    unsigned short* hidden_g = (unsigned short*)alloc((size_t)NN * KD * 2);
    unsigned short* gcn_pre  = (unsigned short*)alloc((size_t)NN * 128 * 2);

    hipMemsetAsync(deg, 0, (size_t)NN * 4, stream);

    int eblk = (NE + 255) / 256;
    k_count<<<eblk, 256, 0, stream>>>(dst, deg);
    k_chunk_sum<<<NCH, 256, 0, stream>>>(deg, chunkSum);
    k_scan_chunks<<<1, 256, 0, stream>>>(chunkSum, chunkOff);
    k_scan_write<<<NCH, 256, 0, stream>>>(deg, chunkOff, offsets, cursor);
    k_scatter<<<eblk, 256, 0, stream>>>(src, dst, ew, cursor, pedge);

    k_convW<<<256, 256, 0, stream>>>(hw, mw_, lw, Wht, Wmlt);

    int mblk = (NN + 127) / 128;
    k_gemm<0, 0><<<dim3(mblk, 2), 256, 0, stream>>>(input, Wht, hb, mb, lb, support, 256);
    k_spmm1<<<NN / 4, 256, 0, stream>>>(offsets, pedge, support, hb, hidden_g);
    k_gemm<1, 0><<<dim3(mblk, 1), 256, 0, stream>>>(hidden_g, Wmlt, hb, mb, lb, gcn_pre, 128);
    k_gemm<2, 1><<<dim3(mblk, 1), 256, 0, stream>>>(support, Wmlt, hb, mb, lb, out, 128);
    k_spmm2<<<NN / 4, 256, 0, stream>>>(offsets, pedge, gcn_pre, mixw, out);
}

// Round 5
// 241.807 us; speedup vs baseline: 1.0872x; 1.0750x over previous
//
#include <hip/hip_runtime.h>
#include <math.h>

#define NN 50000
#define NE 800000
#define KD 256
#define OD 64
#define NCH ((NN + 255) / 256)   // 196 <= 256

#define QS 32.0f      // int8 quant scale (fixed, power of 2)
#define IQS (1.0f / 32.0f)

using bf16x8 = __attribute__((ext_vector_type(8))) short;
using f32x4  = __attribute__((ext_vector_type(4))) float;

__device__ __forceinline__ unsigned short f2b(float x) {
    union { float f; unsigned u; } c; c.f = x;
    unsigned r = (c.u + 0x7FFF + ((c.u >> 16) & 1)) >> 16;
    return (unsigned short)r;
}
__device__ __forceinline__ float b2f(unsigned short b) {
    union { unsigned u; float f; } c; c.u = ((unsigned)b) << 16;
    return c.f;
}
__device__ __forceinline__ signed char quant8(float v) {
    int q = __float2int_rn(v * QS);
    q = q > 127 ? 127 : (q < -127 ? -127 : q);
    return (signed char)q;
}

// ---------------- CSR build ----------------

__global__ void k_count(const int* __restrict__ dst, int* __restrict__ deg) {
    int e = blockIdx.x * 256 + threadIdx.x;
    if (e < NE) atomicAdd(&deg[dst[e]], 1);
}

__global__ void k_chunk_sum(const int* __restrict__ deg, int* __restrict__ chunkSum) {
    __shared__ int s[256];
    int g = blockIdx.x * 256 + threadIdx.x;
    s[threadIdx.x] = (g < NN) ? deg[g] : 0;
    __syncthreads();
    for (int o = 128; o > 0; o >>= 1) {
        if (threadIdx.x < o) s[threadIdx.x] += s[threadIdx.x + o];
        __syncthreads();
    }
    if (threadIdx.x == 0) chunkSum[blockIdx.x] = s[0];
}

__global__ void k_scan_chunks(const int* __restrict__ chunkSum, int* __restrict__ chunkOff) {
    __shared__ int s[256];
    int t = threadIdx.x;
    int v = (t < NCH) ? chunkSum[t] : 0;
    s[t] = v;
    __syncthreads();
    for (int o = 1; o < 256; o <<= 1) {
        int x = (t >= o) ? s[t - o] : 0;
        __syncthreads();
        s[t] += x;
        __syncthreads();
    }
    if (t < NCH) chunkOff[t] = s[t] - v;
}

__global__ void k_scan_write(const int* __restrict__ deg, const int* __restrict__ chunkOff,
                             int* __restrict__ offsets, int* __restrict__ cursor) {
    __shared__ int s[256];
    int b = blockIdx.x, t = threadIdx.x;
    int g = b * 256 + t;
    int v = (g < NN) ? deg[g] : 0;
    s[t] = v;
    __syncthreads();
    for (int o = 1; o < 256; o <<= 1) {
        int x = (t >= o) ? s[t - o] : 0;
        __syncthreads();
        s[t] += x;
        __syncthreads();
    }
    int excl = s[t] - v + chunkOff[b];
    if (g <= NN) {
        offsets[g] = excl;
        if (g < NN) cursor[g] = excl;
    }
}

__global__ void k_scatter(const int* __restrict__ src, const int* __restrict__ dst,
                          const float* __restrict__ w, int* __restrict__ cursor,
                          int2* __restrict__ pedge) {
    int e = blockIdx.x * 256 + threadIdx.x;
    if (e < NE) {
        int d = dst[e];
        int p = atomicAdd(&cursor[d], 1);
        pedge[p] = make_int2(src[e], __float_as_int(w[e]));
    }
}

// ---------------- weight transpose + bf16 convert (one-time, tiny) ----------------

__global__ void k_convW(const float* __restrict__ hw, const float* __restrict__ mw_,
                        const float* __restrict__ lw,
                        unsigned short* __restrict__ Wht, unsigned short* __restrict__ Wmlt) {
    int idx = blockIdx.x * 256 + threadIdx.x;
    if (idx < 256 * 256) {
        int n = idx >> 8, k = idx & 255;
        Wht[(size_t)n * 256 + k] = f2b(hw[(size_t)k * 256 + n]);
    }
    if (idx < 128 * 256) {
        int n = idx >> 8, k = idx & 255;
        float v = (n < 64) ? mw_[(size_t)k * 64 + n] : lw[(size_t)k * 64 + (n - 64)];
        Wmlt[(size_t)n * 256 + k] = f2b(v);
    }
}

// ---------------- MFMA GEMM: 128x128 block tile, 4 waves, wave-tile 64x64 ----------------
// AM: 0 = A f32 (convert on the fly); 1 = A bf16; 2 = A bf16 + hbias + relu
// EM: 2 = bf16 (ld 256) to Outp AND int8 (ld 256) to Outp2        [gemm1]
//     3 = int8 only (ld 128) to Outp                              [gemm2 GCN]
//     4 = bf16 + region bias (ld 128) to Outp                     [gemm2 MLP]

template <int AM, int EM>
__global__ __launch_bounds__(256) void k_gemm(const void* __restrict__ Ap,
                                              const unsigned short* __restrict__ Bt,
                                              const float* __restrict__ hbias,
                                              const float* __restrict__ mbias,
                                              const float* __restrict__ lbias,
                                              void* __restrict__ Outp,
                                              void* __restrict__ Outp2) {
    __shared__ unsigned short As[128 * 64];
    __shared__ unsigned short Bs[128 * 64];
    const int tid = threadIdx.x;
    const int row0 = blockIdx.x * 128;
    const int n0 = blockIdx.y * 128;
    const int lane = tid & 63;
    const int w = tid >> 6, wm = w >> 1, wn = w & 1;
    const int lr = lane & 15, lg = lane >> 4;
    const int r = tid >> 1;       // staging row 0..127
    const int h = tid & 1;        // k-half (32 bf16)

    f32x4 acc[4][4] = {};

    for (int k0 = 0; k0 < KD; k0 += 64) {
        {
            int gr = row0 + r;
            unsigned short tmp[32];
            if (AM == 0) {
                const float* A = (const float*)Ap;
                if (gr < NN) {
                    #pragma unroll
                    for (int i = 0; i < 8; ++i) {
                        float4 v = *reinterpret_cast<const float4*>(
                            &A[(size_t)gr * KD + k0 + h * 32 + i * 4]);
                        tmp[i * 4 + 0] = f2b(v.x); tmp[i * 4 + 1] = f2b(v.y);
                        tmp[i * 4 + 2] = f2b(v.z); tmp[i * 4 + 3] = f2b(v.w);
                    }
                } else {
                    #pragma unroll
                    for (int i = 0; i < 32; ++i) tmp[i] = 0;
                }
            } else {
                const unsigned short* A = (const unsigned short*)Ap;
                if (gr < NN) {
                    #pragma unroll
                    for (int i = 0; i < 4; ++i)
                        *reinterpret_cast<uint4*>(&tmp[i * 8]) =
                            *reinterpret_cast<const uint4*>(&A[(size_t)gr * KD + k0 + h * 32 + i * 8]);
                    if (AM == 2) {
                        #pragma unroll
                        for (int i = 0; i < 8; ++i) {
                            float4 hb4 = *reinterpret_cast<const float4*>(&hbias[k0 + h * 32 + i * 4]);
                            tmp[i * 4 + 0] = f2b(fmaxf(b2f(tmp[i * 4 + 0]) + hb4.x, 0.f));
                            tmp[i * 4 + 1] = f2b(fmaxf(b2f(tmp[i * 4 + 1]) + hb4.y, 0.f));
                            tmp[i * 4 + 2] = f2b(fmaxf(b2f(tmp[i * 4 + 2]) + hb4.z, 0.f));
                            tmp[i * 4 + 3] = f2b(fmaxf(b2f(tmp[i * 4 + 3]) + hb4.w, 0.f));
                        }
                    }
                } else {
                    #pragma unroll
                    for (int i = 0; i < 32; ++i) tmp[i] = 0;
                }
            }
            #pragma unroll
            for (int i = 0; i < 4; ++i) {
                int slot = (h * 4 + i) ^ (r & 7);
                *reinterpret_cast<uint4*>(&As[r * 64 + slot * 8]) =
                    *reinterpret_cast<const uint4*>(&tmp[i * 8]);
            }
        }
        {
            const unsigned short* B = Bt + (size_t)(n0 + r) * KD + k0 + h * 32;
            #pragma unroll
            for (int i = 0; i < 4; ++i) {
                uint4 u = *reinterpret_cast<const uint4*>(B + i * 8);
                int slot = (h * 4 + i) ^ (r & 7);
                *reinterpret_cast<uint4*>(&Bs[r * 64 + slot * 8]) = u;
            }
        }
        __syncthreads();
        const int sa = lr & 7;
        #pragma unroll
        for (int ks = 0; ks < 2; ++ks) {
            int slot = ks * 4 + lg;
            bf16x8 a[4], b[4];
            #pragma unroll
            for (int fm = 0; fm < 4; ++fm) {
                int ra = wm * 64 + fm * 16 + lr;
                a[fm] = *reinterpret_cast<const bf16x8*>(&As[ra * 64 + (slot ^ sa) * 8]);
            }
            #pragma unroll
            for (int fn = 0; fn < 4; ++fn) {
                int rb = wn * 64 + fn * 16 + lr;
                b[fn] = *reinterpret_cast<const bf16x8*>(&Bs[rb * 64 + (slot ^ sa) * 8]);
            }
            #pragma unroll
            for (int fm = 0; fm < 4; ++fm)
                #pragma unroll
                for (int fn = 0; fn < 4; ++fn)
                    acc[fm][fn] = __builtin_amdgcn_mfma_f32_16x16x32_bf16(a[fm], b[fn], acc[fm][fn], 0, 0, 0);
        }
        __syncthreads();
    }
    #pragma unroll
    for (int fm = 0; fm < 4; ++fm) {
        #pragma unroll
        for (int j = 0; j < 4; ++j) {
            int grow = row0 + wm * 64 + fm * 16 + lg * 4 + j;
            if (grow >= NN) continue;
            #pragma unroll
            for (int fn = 0; fn < 4; ++fn) {
                int gcol = n0 + wn * 64 + fn * 16 + lr;
                float v = acc[fm][fn][j];
                if (EM == 2) {
                    ((unsigned short*)Outp)[(size_t)grow * 256 + gcol] = f2b(v);
                    ((signed char*)Outp2)[(size_t)grow * 256 + gcol] = quant8(v);
                } else if (EM == 3) {
                    ((signed char*)Outp)[(size_t)grow * 128 + gcol] = quant8(v);
                } else {  // EM == 4
                    float b = (gcol < 64) ? mbias[gcol] : lbias[gcol - 64];
                    ((unsigned short*)Outp)[(size_t)grow * 128 + gcol] = f2b(v + b);
                }
            }
        }
    }
}

// ---------------- SpMM1 (int8 gather) + bias + relu -> hidden_g bf16 ----------------

__global__ __launch_bounds__(256) void k_spmm1(const int* __restrict__ off,
                                               const int2* __restrict__ pedge,
                                               const unsigned* __restrict__ supq,   // [NN][64] u32 (4 int8)
                                               const float* __restrict__ bias,
                                               unsigned short* __restrict__ hg) {
    int lane = threadIdx.x & 63;
    int d = blockIdx.x * 4 + (threadIdx.x >> 6);
    int e0 = off[d], e1 = off[d + 1];
    float a0 = 0.f, a1 = 0.f, a2 = 0.f, a3 = 0.f;
    int e = e0;
    for (; e + 8 <= e1; e += 8) {
        int2 E[8];
        unsigned U[8];
        #pragma unroll
        for (int i = 0; i < 8; ++i) E[i] = pedge[e + i];
        #pragma unroll
        for (int i = 0; i < 8; ++i) U[i] = supq[(size_t)E[i].x * 64 + lane];
        #pragma unroll
        for (int i = 0; i < 8; ++i) {
            float w = __int_as_float(E[i].y);
            unsigned u = U[i];
            a0 = fmaf(w, (float)((int)(signed char)(u)), a0);
            a1 = fmaf(w, (float)((int)(signed char)(u >> 8)), a1);
            a2 = fmaf(w, (float)((int)(signed char)(u >> 16)), a2);
            a3 = fmaf(w, (float)((int)(signed char)(u >> 24)), a3);
        }
    }
    for (; e < e1; ++e) {
        int2 E = pedge[e];
        float w = __int_as_float(E.y);
        unsigned u = supq[(size_t)E.x * 64 + lane];
        a0 = fmaf(w, (float)((int)(signed char)(u)), a0);
        a1 = fmaf(w, (float)((int)(signed char)(u >> 8)), a1);
        a2 = fmaf(w, (float)((int)(signed char)(u >> 16)), a2);
        a3 = fmaf(w, (float)((int)(signed char)(u >> 24)), a3);
    }
    float4 b = *reinterpret_cast<const float4*>(&bias[lane * 4]);
    ushort4 o;
    o.x = f2b(fmaxf(a0 * IQS + b.x, 0.f));
    o.y = f2b(fmaxf(a1 * IQS + b.y, 0.f));
    o.z = f2b(fmaxf(a2 * IQS + b.z, 0.f));
    o.w = f2b(fmaxf(a3 * IQS + b.w, 0.f));
    reinterpret_cast<ushort4*>(hg)[(size_t)d * 64 + lane] = o;
}

// ---------------- SpMM2 (int8 gather, 128 dims) + mixture with mlp (write-once) ----------------

__global__ __launch_bounds__(256) void k_spmm2(const int* __restrict__ off,
                                               const int2* __restrict__ pedge,
                                               const unsigned short* __restrict__ gq,  // [NN][64] u16 (2 int8)
                                               const unsigned short* __restrict__ mlp, // [NN][128] bf16
                                               const float* __restrict__ mixw,
                                               float* __restrict__ out) {
    int lane = threadIdx.x & 63;
    int d = blockIdx.x * 4 + (threadIdx.x >> 6);
    int e0 = off[d], e1 = off[d + 1];
    float a0 = 0.f, a1 = 0.f;
    int e = e0;
    for (; e + 8 <= e1; e += 8) {
        int2 E[8];
        unsigned short U[8];
        #pragma unroll
        for (int i = 0; i < 8; ++i) E[i] = pedge[e + i];
        #pragma unroll
        for (int i = 0; i < 8; ++i) U[i] = gq[(size_t)E[i].x * 64 + lane];
        #pragma unroll
        for (int i = 0; i < 8; ++i) {
            float w = __int_as_float(E[i].y);
            a0 = fmaf(w, (float)((int)(signed char)(U[i] & 0xff)), a0);
            a1 = fmaf(w, (float)((int)(signed char)(U[i] >> 8)), a1);
        }
    }
    for (; e < e1; ++e) {
        int2 E = pedge[e];
        float w = __int_as_float(E.y);
        unsigned short u = gq[(size_t)E.x * 64 + lane];
        a0 = fmaf(w, (float)((int)(signed char)(u & 0xff)), a0);
        a1 = fmaf(w, (float)((int)(signed char)(u >> 8)), a1);
    }
    float g0 = a0 * IQS, g1 = a1 * IQS;
    ushort2 mu = reinterpret_cast<const ushort2*>(mlp)[(size_t)d * 64 + lane];
    float m0 = b2f(mu.x), m1 = b2f(mu.y);
    float mw = mixw[0];
    float mr = 1.f / (1.f + expf(-mw));
    int c = lane * 2;
    if (c < 64) {
        *reinterpret_cast<float2*>(out + (size_t)d * OD + c) =
            make_float2(g0 * mw + m0 * (1.f - mw), g1 * mw + m1 * (1.f - mw));
    } else {
        *reinterpret_cast<float2*>(out + (size_t)NN * OD + (size_t)d * OD + (c - 64)) =
            make_float2(g0 * mr + m0 * (1.f - mr), g1 * mr + m1 * (1.f - mr));
    }
}

// ---------------- host ----------------

extern "C" void kernel_launch(void* const* d_in, const int* in_sizes, int n_in,
                              void* d_out, int out_size, void* d_ws, size_t ws_size,
                              hipStream_t stream) {
    const float* input = (const float*)d_in[0];
    const int*   ei    = (const int*)d_in[1];
    const float* ew    = (const float*)d_in[2];
    const float* mixw  = (const float*)d_in[3];
    const float* hw    = (const float*)d_in[4];
    const float* hb    = (const float*)d_in[5];
    const float* mw_   = (const float*)d_in[6];
    const float* mb    = (const float*)d_in[7];
    const float* lw    = (const float*)d_in[8];
    const float* lb    = (const float*)d_in[9];
    float* out = (float*)d_out;

    const int* src = ei;
    const int* dst = ei + NE;

    char* ws = (char*)d_ws;
    size_t off = 0;
    auto alloc = [&](size_t bytes) -> void* {
        void* p = ws + off;
        off += (bytes + 255) & ~(size_t)255;
        return p;
    };
    int*   deg      = (int*)alloc((size_t)NN * 4);
    int*   offsets  = (int*)alloc((size_t)(NN + 1) * 4);
    int*   cursor   = (int*)alloc((size_t)NN * 4);
    int*   chunkSum = (int*)alloc((size_t)NCH * 4);
    int*   chunkOff = (int*)alloc((size_t)NCH * 4);
    int2*  pedge    = (int2*)alloc((size_t)NE * 8);
    unsigned short* Wht  = (unsigned short*)alloc((size_t)256 * 256 * 2);
    unsigned short* Wmlt = (unsigned short*)alloc((size_t)128 * 256 * 2);
    unsigned short* support  = (unsigned short*)alloc((size_t)NN * KD * 2);  // bf16 (MLP path)
    signed char*    supq     = (signed char*)alloc((size_t)NN * KD);        // int8 (gather)
    unsigned short* hidden_g = (unsigned short*)alloc((size_t)NN * KD * 2);  // bf16
    signed char*    gcnq     = (signed char*)alloc((size_t)NN * 128);       // int8 (gather)
    unsigned short* mlp      = (unsigned short*)alloc((size_t)NN * 128 * 2); // bf16

    hipMemsetAsync(deg, 0, (size_t)NN * 4, stream);

    int eblk = (NE + 255) / 256;
    k_count<<<eblk, 256, 0, stream>>>(dst, deg);
    k_chunk_sum<<<NCH, 256, 0, stream>>>(deg, chunkSum);
    k_scan_chunks<<<1, 256, 0, stream>>>(chunkSum, chunkOff);
    k_scan_write<<<NCH, 256, 0, stream>>>(deg, chunkOff, offsets, cursor);
    k_scatter<<<eblk, 256, 0, stream>>>(src, dst, ew, cursor, pedge);

    k_convW<<<256, 256, 0, stream>>>(hw, mw_, lw, Wht, Wmlt);

    int mblk = (NN + 127) / 128;
    // GEMM1: support(bf16) + supq(int8) = bf16(input) @ hw
    k_gemm<0, 2><<<dim3(mblk, 2), 256, 0, stream>>>(input, Wht, hb, mb, lb, support, supq);
    // SpMM1 (int8 gather) + bias + relu -> hidden_g (bf16)
    k_spmm1<<<NN / 4, 256, 0, stream>>>(offsets, pedge, (const unsigned*)supq, hb, hidden_g);
    // GEMM2 (GCN): gcnq(int8) = hidden_g @ [mw|lw]
    k_gemm<1, 3><<<dim3(mblk, 1), 256, 0, stream>>>(hidden_g, Wmlt, hb, mb, lb, gcnq, nullptr);
    // GEMM2 (MLP): mlp(bf16) = relu(support+hb) @ [mw|lw] + [mb|lb]
    k_gemm<2, 4><<<dim3(mblk, 1), 256, 0, stream>>>(support, Wmlt, hb, mb, lb, mlp, nullptr);
    // SpMM2 (int8 gather) + mixture combine with mlp -> d_out (write-once)
    k_spmm2<<<NN / 4, 256, 0, stream>>>(offsets, pedge, (const unsigned short*)gcnq, mlp, mixw, out);
}